// Round 4
// baseline (299.587 us; speedup 1.0000x reference)
//
#include <hip/hip_runtime.h>
#include <math.h>

#define NP 16384
#define NR 8192

typedef __attribute__((ext_vector_type(8))) short short8;
typedef __attribute__((ext_vector_type(4))) float f32x4;

__device__ inline unsigned short f2b(float f) {
  unsigned int x = __float_as_uint(f);
  return (unsigned short)((x + 0x7FFFu + ((x >> 16) & 1u)) >> 16);  // RNE
}
__device__ inline float blo(unsigned int u) { return __uint_as_float(u << 16); }
__device__ inline float bhi(unsigned int u) { return __uint_as_float(u & 0xffff0000u); }

// ---------------- convert 8 weight matrices f32 -> bf16 (one kernel)
__global__ __launch_bounds__(256) void k_wconv(const float* __restrict__ s0, const float* __restrict__ s1,
                                               const float* __restrict__ s2, const float* __restrict__ s3,
                                               const float* __restrict__ s4, const float* __restrict__ s5,
                                               const float* __restrict__ s6, const float* __restrict__ s7,
                                               unsigned short* __restrict__ dst) {
  const int sizes[8] = {147456, 49152, 65536, 32768, 25600, 25600, 20480, 16384};
  const int offs[8]  = {0, 147456, 196608, 262144, 294912, 320512, 346112, 366592};
  const float* srcs[8] = {s0, s1, s2, s3, s4, s5, s6, s7};
  int m = blockIdx.y;
  int i = (blockIdx.x * 256 + threadIdx.x) * 8;
  if (i >= sizes[m]) return;
  const float4* sp = (const float4*)(srcs[m] + i);
  float4 a = sp[0], b = sp[1];
  uint4 o;
  o.x = f2b(a.x) | ((unsigned int)f2b(a.y) << 16);
  o.y = f2b(a.z) | ((unsigned int)f2b(a.w) << 16);
  o.z = f2b(b.x) | ((unsigned int)f2b(b.y) << 16);
  o.w = f2b(b.z) | ((unsigned int)f2b(b.w) << 16);
  *(uint4*)(dst + offs[m] + i) = o;
}

// ---------------- transpose rgb_features (128, NR) f32 -> rgbTb (NR+1, 128) bf16
// also packs rgb_xyz (NR,3) -> rxyz4 (NR) float4 for SMEM-friendly nn scan
__global__ __launch_bounds__(256) void k_transpose_rgb(const float* __restrict__ rf,
                                                       const float* __restrict__ rxyz,
                                                       unsigned short* __restrict__ rgbTb,
                                                       float4* __restrict__ rxyz4) {
  __shared__ float tile[128][65];
  int t = threadIdx.x;
  int r0 = blockIdx.x * 64;
  for (int e = 0; e < 32; ++e) {
    int idx = t + e * 256;
    int c = idx >> 6, rl = idx & 63;
    tile[c][rl] = rf[c * NR + r0 + rl];
  }
  __syncthreads();
  for (int e = 0; e < 32; ++e) {
    int idx = t + e * 256;
    int rl = idx >> 7, c = idx & 127;
    rgbTb[(size_t)(r0 + rl) * 128 + c] = f2b(tile[c][rl]);
  }
  if (blockIdx.x == 0 && t < 128) rgbTb[(size_t)NR * 128 + t] = 0;
  int i = blockIdx.x * 64 + (t & 63);
  if ((t >> 6) == 0) {                      // one wave packs this block's 64 xyz rows
    rxyz4[i] = make_float4(rxyz[i * 3], rxyz[i * 3 + 1], rxyz[i * 3 + 2], 0.f);
  }
}

// ---------------- transpose pcd_features (32, NP) f32 -> full[n][0..31] bf16 (ld 160)
__global__ __launch_bounds__(256) void k_transpose_pcd(const float* __restrict__ pf,
                                                       unsigned short* __restrict__ full) {
  __shared__ float tile[32][65];
  int t = threadIdx.x;
  int n0 = blockIdx.x * 64;
  for (int e = 0; e < 8; ++e) {
    int idx = t + e * 256;
    int c = idx >> 6, nl = idx & 63;
    tile[c][nl] = pf[c * NP + n0 + nl];
  }
  __syncthreads();
  for (int e = 0; e < 8; ++e) {
    int idx = t + e * 256;
    int nl = idx >> 5, c = idx & 31;
    full[(size_t)(n0 + nl) * 160 + c] = f2b(tile[c][nl]);
  }
}

// ---------------- three_nn partials: grid (256 groups, 4); 4 waves/block, split s = by*4+w.
// rgb coords read at wave-uniform addresses (-> s_load via scalarize-global-loads); no LDS.
// s-registers init to loose radius sentinel: only in-radius candidates ever insert, and the
// insert is gated by a WAVE-UNIFORM ballot branch (taken ~6% of iters) so the common path
// is 7 VALU ops. Sentinel > R2 so unfilled slots mask to NR exactly like the global-top-k
// reference path.
__global__ __launch_bounds__(256) void k_nn_part(const float* __restrict__ pxyz,
                                                 const float4* __restrict__ rxyz4,
                                                 float* __restrict__ pd,
                                                 int* __restrict__ pi) {
  int t = threadIdx.x;
  int g = blockIdx.x;
  int lane = t & 63, w = t >> 6;
  int s = blockIdx.y * 4 + w;
  int rbase = s * 512;
  int n = g * 64 + lane;
  float px = pxyz[n * 3], py = pxyz[n * 3 + 1], pz = pxyz[n * 3 + 2];
  const float R2L = 0.005626125f;          // 0.075^2 * 1.0002 (loose filter sentinel)
  float s0 = R2L, s1 = R2L, s2 = R2L;
  int i0 = 0, i1 = 0, i2 = 0;
#pragma unroll 8
  for (int loc = 0; loc < 512; ++loc) {
    float4 r = rxyz4[rbase + loc];         // uniform address -> SMEM
    float dx = px - r.x, dy = py - r.y, dz = pz - r.z;
    float d2 = fmaf(dx, dx, fmaf(dy, dy, dz * dz));
    if (__ballot(d2 < s2)) {               // wave-uniform branch, rarely taken
      if (d2 < s2) {
        int i = rbase + loc;
        if (d2 < s1) {
          s2 = s1; i2 = i1;
          if (d2 < s0) { s1 = s0; i1 = i0; s0 = d2; i0 = i; }
          else         { s1 = d2; i1 = i; }
        } else { s2 = d2; i2 = i; }
      }
    }
  }
  int off = ((g * 16 + s) * 64 + lane) * 3;
  pd[off + 0] = s0; pd[off + 1] = s1; pd[off + 2] = s2;
  pi[off + 0] = i0; pi[off + 1] = i1; pi[off + 2] = i2;
}

// ---------------- merge 16 split-partials per point, radius mask, write neighbors
__global__ __launch_bounds__(256) void k_nn_merge(const float* __restrict__ pd,
                                                  const int* __restrict__ pi,
                                                  int* __restrict__ nb) {
  int n = blockIdx.x * 256 + threadIdx.x;
  int g = n >> 6, l = n & 63;
  float s0 = 3.4e38f, s1 = 3.4e38f, s2 = 3.4e38f;
  int i0 = 0, i1 = 0, i2 = 0;
  for (int s = 0; s < 16; ++s) {           // ascending split order: tie-break correct
    int off = ((g * 16 + s) * 64 + l) * 3;
#pragma unroll
    for (int q = 0; q < 3; ++q) {
      float d2 = pd[off + q]; int i = pi[off + q];
      if (d2 < s2) {
        if (d2 < s1) {
          s2 = s1; i2 = i1;
          if (d2 < s0) { s1 = s0; i1 = i0; s0 = d2; i0 = i; }
          else         { s1 = d2; i1 = i; }
        } else { s2 = d2; i2 = i; }
      }
    }
  }
  const float R2 = 0.075f * 0.075f;        // same mask as all passing rounds
  nb[n * 3 + 0] = (s0 > R2) ? NR : i0;
  nb[n * 3 + 1] = (s1 > R2) ? NR : i1;
  nb[n * 3 + 2] = (s2 > R2) ? NR : i2;
}

// ---------------- gather 3 neighbor rows -> xcat row (384 bf16) + elementwise max -> x2[n][128..255]
__global__ __launch_bounds__(256) void k_gather_max(const unsigned short* __restrict__ rgbTb,
                                                    const int* __restrict__ nb,
                                                    unsigned short* __restrict__ xcat,
                                                    unsigned short* __restrict__ x2) {
  int t = threadIdx.x, lane = t & 63, w = t >> 6;
  int n = blockIdx.x * 4 + w;
  int j0 = nb[n * 3 + 0], j1 = nb[n * 3 + 1], j2 = nb[n * 3 + 2];
  unsigned int a = ((const unsigned int*)(rgbTb + (size_t)j0 * 128))[lane];
  unsigned int b = ((const unsigned int*)(rgbTb + (size_t)j1 * 128))[lane];
  unsigned int c = ((const unsigned int*)(rgbTb + (size_t)j2 * 128))[lane];
  unsigned int* xr = (unsigned int*)(xcat + (size_t)n * 384);
  xr[lane] = a; xr[64 + lane] = b; xr[128 + lane] = c;
  float ml = fmaxf(blo(a), fmaxf(blo(b), blo(c)));
  float mh = fmaxf(bhi(a), fmaxf(bhi(b), bhi(c)));
  unsigned int m = (__float_as_uint(mh) & 0xffff0000u) | (__float_as_uint(ml) >> 16);
  ((unsigned int*)(x2 + (size_t)n * 256 + 128))[lane] = m;
}

// ---------------- bf16 MFMA GEMM: Y[n][o] = act(sc[o]*(W X)[o][n] + sh[o])
template <bool BN, bool RELU>
__global__ __launch_bounds__(256) void k_bgemm(const unsigned short* __restrict__ Wb,
                                               const float* __restrict__ bias,
                                               const float* __restrict__ bnp,
                                               const unsigned short* __restrict__ X,
                                               unsigned short* __restrict__ Y,
                                               int O, int C, int ldY) {
  __shared__ unsigned short Xs[128 * 40];  // 32k per row + 8 pad (2-way banks = free)
  __shared__ unsigned short Wl[128 * 40];
  __shared__ float scsh[256];
  int t = threadIdx.x;
  int lane = t & 63, w = t >> 6;
  int wn = w & 1, wm = w >> 1;
  int q = lane >> 4, l15 = lane & 15;
  int n0 = blockIdx.x * 128, o0 = blockIdx.y * 128;
  if (t < 128) {
    int o = o0 + t;
    float sc = 0.f, sh = 0.f;
    if (o < O) {
      float b = bias[o];
      if (BN) {
        float g = bnp[o], be = bnp[O + o], m = bnp[2 * O + o], v = bnp[3 * O + o];
        float inv = g * rsqrtf(v + 1e-5f);
        sc = inv; sh = (b - m) * inv + be;
      } else { sc = 1.f; sh = b; }
    }
    scsh[t] = sc; scsh[128 + t] = sh;
  }
  f32x4 acc[4][4] = {};
  for (int c0 = 0; c0 < C; c0 += 32) {
    __syncthreads();
#pragma unroll
    for (int e = 0; e < 2; ++e) {
      int idx = e * 256 + t;
      int row = idx >> 2, kb = idx & 3;
      uint4 xv = *(const uint4*)(X + (size_t)(n0 + row) * C + c0 + kb * 8);
      *(uint4*)&Xs[row * 40 + kb * 8] = xv;
      int go = o0 + row; if (go >= O) go = O - 1;       // clamp; masked at store
      uint4 wv = *(const uint4*)(Wb + (size_t)go * C + c0 + kb * 8);
      *(uint4*)&Wl[row * 40 + kb * 8] = wv;
    }
    __syncthreads();
    short8 af[4], bf[4];
#pragma unroll
    for (int a = 0; a < 4; ++a)
      af[a] = *(const short8*)&Wl[(wm * 64 + a * 16 + l15) * 40 + q * 8];
#pragma unroll
    for (int b = 0; b < 4; ++b)
      bf[b] = *(const short8*)&Xs[(wn * 64 + b * 16 + l15) * 40 + q * 8];
#pragma unroll
    for (int a = 0; a < 4; ++a)
#pragma unroll
      for (int b = 0; b < 4; ++b)
        acc[a][b] = __builtin_amdgcn_mfma_f32_16x16x32_bf16(af[a], bf[b], acc[a][b], 0, 0, 0);
  }
  __syncthreads();
  float* lt = (w < 2) ? ((float*)Xs + w * 1280) : ((float*)Wl + (w - 2) * 1280);
#pragma unroll
  for (int a = 0; a < 4; ++a) {
    int oTile = wm * 64 + a * 16;
    if (o0 + oTile >= O) continue;
    float scr[4], shr[4];
#pragma unroll
    for (int r = 0; r < 4; ++r) {
      scr[r] = scsh[oTile + q * 4 + r];
      shr[r] = scsh[128 + oTile + q * 4 + r];
    }
#pragma unroll
    for (int b = 0; b < 4; ++b) {
      int nl = b * 16 + l15;
      f32x4 v;
#pragma unroll
      for (int r = 0; r < 4; ++r) {
        float x = acc[a][b][r] * scr[r] + shr[r];
        if (RELU) x = fmaxf(x, 0.f);
        v[r] = x;
      }
      *(f32x4*)&lt[nl * 20 + q * 4] = v;
    }
#pragma unroll
    for (int g = 0; g < 4; ++g) {
      int nl = g * 16 + (lane >> 2);
      int ob = (lane & 3) * 4;
      f32x4 v = *(const f32x4*)&lt[nl * 20 + ob];
      ushort4 u;
      u.x = f2b(v[0]); u.y = f2b(v[1]); u.z = f2b(v[2]); u.w = f2b(v[3]);
      *(ushort4*)(Y + (size_t)(n0 + wn * 64 + nl) * ldY + o0 + oTile + ob) = u;
    }
  }
}

// ---------------- fused tail: score head (blocks 0..1023), L2-norm (1024..2047), xyz copy (2048..2095)
__global__ __launch_bounds__(256) void k_tail(const unsigned short* __restrict__ S,
                                              const unsigned short* __restrict__ FP,
                                              const float* __restrict__ wv,
                                              const float* __restrict__ bv,
                                              const float* __restrict__ pxyz,
                                              float* __restrict__ out) {
  int b = blockIdx.x;
  int t = threadIdx.x, lane = t & 63, w = t >> 6;
  if (b < 1024) {
    int row = b * 16 + w * 4 + (lane >> 4);
    int col8 = (lane & 15) * 8;
    uint4 raw = *(const uint4*)(S + (size_t)row * 128 + col8);
    float4 w0 = *(const float4*)(wv + col8);
    float4 w1 = *(const float4*)(wv + col8 + 4);
    float acc = blo(raw.x) * w0.x + bhi(raw.x) * w0.y + blo(raw.y) * w0.z + bhi(raw.y) * w0.w +
                blo(raw.z) * w1.x + bhi(raw.z) * w1.y + blo(raw.w) * w1.z + bhi(raw.w) * w1.w;
    acc += __shfl_xor(acc, 1); acc += __shfl_xor(acc, 2);
    acc += __shfl_xor(acc, 4); acc += __shfl_xor(acc, 8);
    if ((lane & 15) == 0) out[49152 + row] = 1.f / (1.f + expf(-(acc + bv[0])));
  } else if (b < 2048) {
    int row = (b - 1024) * 16 + w * 4 + (lane >> 4);
    int col8 = (lane & 15) * 8;
    uint4 raw = *(const uint4*)(FP + (size_t)row * 128 + col8);
    float v[8] = {blo(raw.x), bhi(raw.x), blo(raw.y), bhi(raw.y),
                  blo(raw.z), bhi(raw.z), blo(raw.w), bhi(raw.w)};
    float s = 0.f;
#pragma unroll
    for (int i = 0; i < 8; ++i) s = fmaf(v[i], v[i], s);
    s += __shfl_xor(s, 1); s += __shfl_xor(s, 2);
    s += __shfl_xor(s, 4); s += __shfl_xor(s, 8);
    float inv = 1.f / fmaxf(sqrtf(s), 1e-12f);
    float* op = out + 65536 + (size_t)row * 128 + col8;
    *(float4*)op = make_float4(v[0] * inv, v[1] * inv, v[2] * inv, v[3] * inv);
    *(float4*)(op + 4) = make_float4(v[4] * inv, v[5] * inv, v[6] * inv, v[7] * inv);
  } else {
    int i = (b - 2048) * 256 + t;
    ((float4*)out)[i] = ((const float4*)pxyz)[i];
  }
}

extern "C" void kernel_launch(void* const* d_in, const int* in_sizes, int n_in,
                              void* d_out, int out_size, void* d_ws, size_t ws_size,
                              hipStream_t stream) {
  const float* pcd_xyz = (const float*)d_in[0];
  const float* rgb_xyz = (const float*)d_in[1];
  const float* pcd_f   = (const float*)d_in[2];
  const float* rgb_f   = (const float*)d_in[3];
  const float* cc1_w = (const float*)d_in[4];  const float* cc1_b = (const float*)d_in[5];
  const float* cc_bn = (const float*)d_in[6];
  const float* cc2_w = (const float*)d_in[7];  const float* cc2_b = (const float*)d_in[8];
  const float* co1_w = (const float*)d_in[9];  const float* co1_b = (const float*)d_in[10];
  const float* co_bn = (const float*)d_in[11];
  const float* co2_w = (const float*)d_in[12]; const float* co2_b = (const float*)d_in[13];
  const float* dh1_w = (const float*)d_in[14]; const float* dh1_b = (const float*)d_in[15];
  const float* dh1_bn = (const float*)d_in[16];
  const float* dh2_w = (const float*)d_in[17]; const float* dh2_b = (const float*)d_in[18];
  const float* dh2_bn = (const float*)d_in[19];
  const float* dh3_w = (const float*)d_in[20]; const float* dh3_b = (const float*)d_in[21];
  const float* sh1_w = (const float*)d_in[22]; const float* sh1_b = (const float*)d_in[23];
  const float* sh_bn = (const float*)d_in[24];
  const float* sh2_w = (const float*)d_in[25]; const float* sh2_b = (const float*)d_in[26];

  char* ws = (char*)d_ws;
  float* out = (float*)d_out;

  unsigned short* wb    = (unsigned short*)(ws);              // 766 KB
  unsigned short* rgbTb = (unsigned short*)(ws + 0x100000);   // 2.1 MB
  float4* rxyz4         = (float4*)(ws + 0x320000);           // 128 KB
  int*   nb  = (int*)(ws + 0x340000);                         // 192 KB
  float* pd  = (float*)(ws + 0x400000);                       // 3 MB
  int*   pi  = (int*)(ws + 0x700000);                         // 3 MB
  unsigned short* xcat = (unsigned short*)(ws + 0xA00000);    // (NP,384)
  unsigned short* h1   = (unsigned short*)(ws + 0x1700000);   // (NP,384)
  unsigned short* x2   = (unsigned short*)(ws + 0x2300000);   // (NP,256)
  unsigned short* h2   = (unsigned short*)(ws + 0x2B00000);   // (NP,256)
  unsigned short* full = (unsigned short*)(ws + 0x3300000);   // (NP,160)
  unsigned short* h3   = (unsigned short*)(ws + 0x3900000);   // (NP,160)
  unsigned short* h4   = (unsigned short*)(ws + 0x3F00000);   // (NP,160)
  unsigned short* fp   = (unsigned short*)(ws + 0x4500000);   // (NP,128)
  unsigned short* sB   = (unsigned short*)(ws + 0x4A00000);   // (NP,128)

  unsigned short* wb_cc1 = wb;
  unsigned short* wb_cc2 = wb + 147456;
  unsigned short* wb_co1 = wb + 196608;
  unsigned short* wb_co2 = wb + 262144;
  unsigned short* wb_dh1 = wb + 294912;
  unsigned short* wb_dh2 = wb + 320512;
  unsigned short* wb_dh3 = wb + 346112;
  unsigned short* wb_sh1 = wb + 366592;

  k_wconv<<<dim3(72, 8), 256, 0, stream>>>(cc1_w, cc2_w, co1_w, co2_w, dh1_w, dh2_w, dh3_w, sh1_w, wb);
  k_transpose_rgb<<<128, 256, 0, stream>>>(rgb_f, rgb_xyz, rgbTb, rxyz4);
  k_nn_part<<<dim3(256, 4), 256, 0, stream>>>(pcd_xyz, rxyz4, pd, pi);
  k_nn_merge<<<64, 256, 0, stream>>>(pd, pi, nb);
  k_gather_max<<<4096, 256, 0, stream>>>(rgbTb, nb, xcat, x2);
  k_transpose_pcd<<<256, 256, 0, stream>>>(pcd_f, full);

  k_bgemm<true, true><<<dim3(128, 3), 256, 0, stream>>>(wb_cc1, cc1_b, cc_bn, xcat, h1, 384, 384, 384);
  k_bgemm<false, false><<<dim3(128, 1), 256, 0, stream>>>(wb_cc2, cc2_b, nullptr, h1, x2, 128, 384, 256);
  k_bgemm<true, true><<<dim3(128, 2), 256, 0, stream>>>(wb_co1, co1_b, co_bn, x2, h2, 256, 256, 256);
  k_bgemm<false, false><<<dim3(128, 1), 256, 0, stream>>>(wb_co2, co2_b, nullptr, h2, full + 32, 128, 256, 160);
  k_bgemm<true, true><<<dim3(128, 2), 256, 0, stream>>>(wb_dh1, dh1_b, dh1_bn, full, h3, 160, 160, 160);
  k_bgemm<true, true><<<dim3(128, 2), 256, 0, stream>>>(wb_dh2, dh2_b, dh2_bn, h3, h4, 160, 160, 160);
  k_bgemm<false, false><<<dim3(128, 1), 256, 0, stream>>>(wb_dh3, dh3_b, nullptr, h4, fp, 128, 160, 128);
  k_bgemm<true, true><<<dim3(128, 1), 256, 0, stream>>>(wb_sh1, sh1_b, sh_bn, fp, sB, 128, 128, 128);

  k_tail<<<2096, 256, 0, stream>>>(sB, fp, sh2_w, sh2_b, pcd_xyz, out);
}

// Round 6
// 253.834 us; speedup vs baseline: 1.1803x; 1.1803x over previous
//
#include <hip/hip_runtime.h>
#include <math.h>

#define NP 16384
#define NR 8192

typedef __attribute__((ext_vector_type(8))) short short8;
typedef __attribute__((ext_vector_type(4))) float f32x4;

__device__ inline unsigned short f2b(float f) {
  unsigned int x = __float_as_uint(f);
  return (unsigned short)((x + 0x7FFFu + ((x >> 16) & 1u)) >> 16);  // RNE
}
__device__ inline float blo(unsigned int u) { return __uint_as_float(u << 16); }
__device__ inline float bhi(unsigned int u) { return __uint_as_float(u & 0xffff0000u); }

// ---------------- convert 8 weight matrices f32 -> bf16 (one kernel)
__global__ __launch_bounds__(256) void k_wconv(const float* __restrict__ s0, const float* __restrict__ s1,
                                               const float* __restrict__ s2, const float* __restrict__ s3,
                                               const float* __restrict__ s4, const float* __restrict__ s5,
                                               const float* __restrict__ s6, const float* __restrict__ s7,
                                               unsigned short* __restrict__ dst) {
  const int sizes[8] = {147456, 49152, 65536, 32768, 25600, 25600, 20480, 16384};
  const int offs[8]  = {0, 147456, 196608, 262144, 294912, 320512, 346112, 366592};
  const float* srcs[8] = {s0, s1, s2, s3, s4, s5, s6, s7};
  int m = blockIdx.y;
  int i = (blockIdx.x * 256 + threadIdx.x) * 8;
  if (i >= sizes[m]) return;
  const float4* sp = (const float4*)(srcs[m] + i);
  float4 a = sp[0], b = sp[1];
  uint4 o;
  o.x = f2b(a.x) | ((unsigned int)f2b(a.y) << 16);
  o.y = f2b(a.z) | ((unsigned int)f2b(a.w) << 16);
  o.z = f2b(b.x) | ((unsigned int)f2b(b.y) << 16);
  o.w = f2b(b.z) | ((unsigned int)f2b(b.w) << 16);
  *(uint4*)(dst + offs[m] + i) = o;
}

// ---------------- transpose rgb_features (128, NR) f32 -> rgbTb (NR+1, 128) bf16
// also packs rgb_xyz (NR,3) -> rxyz4 (NR) float4 (x, y, z, |r|^2)
__global__ __launch_bounds__(256) void k_transpose_rgb(const float* __restrict__ rf,
                                                       const float* __restrict__ rxyz,
                                                       unsigned short* __restrict__ rgbTb,
                                                       float4* __restrict__ rxyz4) {
  __shared__ float tile[128][65];
  int t = threadIdx.x;
  int r0 = blockIdx.x * 64;
  for (int e = 0; e < 32; ++e) {
    int idx = t + e * 256;
    int c = idx >> 6, rl = idx & 63;
    tile[c][rl] = rf[c * NR + r0 + rl];
  }
  __syncthreads();
  for (int e = 0; e < 32; ++e) {
    int idx = t + e * 256;
    int rl = idx >> 7, c = idx & 127;
    rgbTb[(size_t)(r0 + rl) * 128 + c] = f2b(tile[c][rl]);
  }
  if (blockIdx.x == 0 && t < 128) rgbTb[(size_t)NR * 128 + t] = 0;
  if ((t >> 6) == 0) {                      // one wave packs this block's 64 xyz rows
    int i = blockIdx.x * 64 + (t & 63);
    float x = rxyz[i * 3], y = rxyz[i * 3 + 1], z = rxyz[i * 3 + 2];
    rxyz4[i] = make_float4(x, y, z, fmaf(x, x, fmaf(y, y, z * z)));
  }
}

// ---------------- transpose pcd_features (32, NP) f32 -> full[n][0..31] bf16 (ld 160)
__global__ __launch_bounds__(256) void k_transpose_pcd(const float* __restrict__ pf,
                                                       unsigned short* __restrict__ full) {
  __shared__ float tile[32][65];
  int t = threadIdx.x;
  int n0 = blockIdx.x * 64;
  for (int e = 0; e < 8; ++e) {
    int idx = t + e * 256;
    int c = idx >> 6, nl = idx & 63;
    tile[c][nl] = pf[c * NP + n0 + nl];
  }
  __syncthreads();
  for (int e = 0; e < 8; ++e) {
    int idx = t + e * 256;
    int nl = idx >> 5, c = idx & 31;
    full[(size_t)(n0 + nl) * 160 + c] = f2b(tile[c][nl]);
  }
}

// ---------------- three_nn partials: LDS broadcast scan + expanded-form prefilter +
// ballot-gated exact insert; 4 waves cover 4x256 candidates; intra-block LDS merge
// (ascending wave order = ascending candidate index => reference tie-break), ONE
// partial per block (fixes R5's inter-wave clobber race). Sentinel R2L > R2 masks
// unfilled slots to NR exactly like the global-top-k reference path (R4-verified).
__global__ __launch_bounds__(256) void k_nn_part(const float* __restrict__ pxyz,
                                                 const float4* __restrict__ rxyz4,
                                                 float* __restrict__ pd,
                                                 int* __restrict__ pi) {
  __shared__ float4 pts[1024];
  __shared__ float msd[4][3][64];
  __shared__ int   mid[4][3][64];
  int t = threadIdx.x;
  int g = blockIdx.x, s = blockIdx.y;
  int lane = t & 63, w = t >> 6;
  int rbase = s * 1024;
#pragma unroll
  for (int e = 0; e < 4; ++e) {
    int q = t + e * 256;
    pts[q] = rxyz4[rbase + q];
  }
  int n = g * 64 + lane;
  float px = pxyz[n * 3], py = pxyz[n * 3 + 1], pz = pxyz[n * 3 + 2];
  float pp = fmaf(px, px, fmaf(py, py, pz * pz));
  float nx2 = -2.f * px, ny2 = -2.f * py, nz2 = -2.f * pz;
  __syncthreads();
  const float R2L = 0.005626125f;          // 0.075^2 * 1.0002 sentinel (> R2 -> masks to NR)
  const float MARGIN = 4e-6f;              // covers fp32 error of expanded form (<=~2.4e-6)
  float s0 = R2L, s1 = R2L, s2 = R2L;
  int i0 = 0, i1 = 0, i2 = 0;
  float thr = R2L + MARGIN - pp;
  int base = w * 256;
#pragma unroll 8
  for (int loc = 0; loc < 256; ++loc) {
    float4 r = pts[base + loc];            // wave-uniform address -> LDS broadcast
    float e3 = fmaf(nz2, r.z, fmaf(ny2, r.y, fmaf(nx2, r.x, r.w)));
    if (__ballot(e3 < thr)) {              // wave-uniform branch, rarely taken
      float dx = px - r.x, dy = py - r.y, dz = pz - r.z;
      float d2 = fmaf(dx, dx, fmaf(dy, dy, dz * dz));
      if (d2 < s2) {                       // exact strict <: reference tie-break
        int i = rbase + base + loc;
        if (d2 < s1) {
          s2 = s1; i2 = i1;
          if (d2 < s0) { s1 = s0; i1 = i0; s0 = d2; i0 = i; }
          else         { s1 = d2; i1 = i; }
        } else { s2 = d2; i2 = i; }
      }
      thr = s2 + MARGIN - pp;
    }
  }
  msd[w][0][lane] = s0; msd[w][1][lane] = s1; msd[w][2][lane] = s2;
  mid[w][0][lane] = i0; mid[w][1][lane] = i1; mid[w][2][lane] = i2;
  __syncthreads();
  if (t < 64) {
    s0 = msd[0][0][t]; s1 = msd[0][1][t]; s2 = msd[0][2][t];
    i0 = mid[0][0][t]; i1 = mid[0][1][t]; i2 = mid[0][2][t];
    for (int ww = 1; ww < 4; ++ww) {       // ascending candidate order: tie-break correct
      for (int q = 0; q < 3; ++q) {
        float d2 = msd[ww][q][t]; int i = mid[ww][q][t];
        if (d2 < s2) {
          if (d2 < s1) {
            s2 = s1; i2 = i1;
            if (d2 < s0) { s1 = s0; i1 = i0; s0 = d2; i0 = i; }
            else         { s1 = d2; i1 = i; }
          } else { s2 = d2; i2 = i; }
        }
      }
    }
    int off = ((g * 8 + s) * 64 + t) * 3;
    pd[off + 0] = s0; pd[off + 1] = s1; pd[off + 2] = s2;
    pi[off + 0] = i0; pi[off + 1] = i1; pi[off + 2] = i2;
  }
}

// ---------------- merge 8 split-partials per point, radius mask, write neighbors
__global__ __launch_bounds__(256) void k_nn_merge(const float* __restrict__ pd,
                                                  const int* __restrict__ pi,
                                                  int* __restrict__ nb) {
  int n = blockIdx.x * 256 + threadIdx.x;
  int g = n >> 6, l = n & 63;
  float s0 = 3.4e38f, s1 = 3.4e38f, s2 = 3.4e38f;
  int i0 = 0, i1 = 0, i2 = 0;
  for (int s = 0; s < 8; ++s) {            // ascending split order: tie-break correct
    int off = ((g * 8 + s) * 64 + l) * 3;
#pragma unroll
    for (int q = 0; q < 3; ++q) {
      float d2 = pd[off + q]; int i = pi[off + q];
      if (d2 < s2) {
        if (d2 < s1) {
          s2 = s1; i2 = i1;
          if (d2 < s0) { s1 = s0; i1 = i0; s0 = d2; i0 = i; }
          else         { s1 = d2; i1 = i; }
        } else { s2 = d2; i2 = i; }
      }
    }
  }
  const float R2 = 0.075f * 0.075f;
  nb[n * 3 + 0] = (s0 > R2) ? NR : i0;
  nb[n * 3 + 1] = (s1 > R2) ? NR : i1;
  nb[n * 3 + 2] = (s2 > R2) ? NR : i2;
}

// ---------------- gather 3 neighbor rows -> xcat row (384 bf16) + elementwise max -> x2[n][128..255]
__global__ __launch_bounds__(256) void k_gather_max(const unsigned short* __restrict__ rgbTb,
                                                    const int* __restrict__ nb,
                                                    unsigned short* __restrict__ xcat,
                                                    unsigned short* __restrict__ x2) {
  int t = threadIdx.x, lane = t & 63, w = t >> 6;
  int n = blockIdx.x * 4 + w;
  int j0 = nb[n * 3 + 0], j1 = nb[n * 3 + 1], j2 = nb[n * 3 + 2];
  unsigned int a = ((const unsigned int*)(rgbTb + (size_t)j0 * 128))[lane];
  unsigned int b = ((const unsigned int*)(rgbTb + (size_t)j1 * 128))[lane];
  unsigned int c = ((const unsigned int*)(rgbTb + (size_t)j2 * 128))[lane];
  unsigned int* xr = (unsigned int*)(xcat + (size_t)n * 384);
  xr[lane] = a; xr[64 + lane] = b; xr[128 + lane] = c;
  float ml = fmaxf(blo(a), fmaxf(blo(b), blo(c)));
  float mh = fmaxf(bhi(a), fmaxf(bhi(b), bhi(c)));
  unsigned int m = (__float_as_uint(mh) & 0xffff0000u) | (__float_as_uint(ml) >> 16);
  ((unsigned int*)(x2 + (size_t)n * 256 + 128))[lane] = m;
}

// ---------------- bf16 MFMA GEMM: Y[n][o] = act(sc[o]*(W X)[o][n] + sh[o])
template <bool BN, bool RELU>
__global__ __launch_bounds__(256) void k_bgemm(const unsigned short* __restrict__ Wb,
                                               const float* __restrict__ bias,
                                               const float* __restrict__ bnp,
                                               const unsigned short* __restrict__ X,
                                               unsigned short* __restrict__ Y,
                                               int O, int C, int ldY) {
  __shared__ unsigned short Xs[128 * 40];  // 32k per row + 8 pad (2-way banks = free)
  __shared__ unsigned short Wl[128 * 40];
  __shared__ float scsh[256];
  int t = threadIdx.x;
  int lane = t & 63, w = t >> 6;
  int wn = w & 1, wm = w >> 1;
  int q = lane >> 4, l15 = lane & 15;
  int n0 = blockIdx.x * 128, o0 = blockIdx.y * 128;
  if (t < 128) {
    int o = o0 + t;
    float sc = 0.f, sh = 0.f;
    if (o < O) {
      float b = bias[o];
      if (BN) {
        float g = bnp[o], be = bnp[O + o], m = bnp[2 * O + o], v = bnp[3 * O + o];
        float inv = g * rsqrtf(v + 1e-5f);
        sc = inv; sh = (b - m) * inv + be;
      } else { sc = 1.f; sh = b; }
    }
    scsh[t] = sc; scsh[128 + t] = sh;
  }
  f32x4 acc[4][4] = {};
  for (int c0 = 0; c0 < C; c0 += 32) {
    __syncthreads();
#pragma unroll
    for (int e = 0; e < 2; ++e) {
      int idx = e * 256 + t;
      int row = idx >> 2, kb = idx & 3;
      uint4 xv = *(const uint4*)(X + (size_t)(n0 + row) * C + c0 + kb * 8);
      *(uint4*)&Xs[row * 40 + kb * 8] = xv;
      int go = o0 + row; if (go >= O) go = O - 1;       // clamp; masked at store
      uint4 wv = *(const uint4*)(Wb + (size_t)go * C + c0 + kb * 8);
      *(uint4*)&Wl[row * 40 + kb * 8] = wv;
    }
    __syncthreads();
    short8 af[4], bf[4];
#pragma unroll
    for (int a = 0; a < 4; ++a)
      af[a] = *(const short8*)&Wl[(wm * 64 + a * 16 + l15) * 40 + q * 8];
#pragma unroll
    for (int b = 0; b < 4; ++b)
      bf[b] = *(const short8*)&Xs[(wn * 64 + b * 16 + l15) * 40 + q * 8];
#pragma unroll
    for (int a = 0; a < 4; ++a)
#pragma unroll
      for (int b = 0; b < 4; ++b)
        acc[a][b] = __builtin_amdgcn_mfma_f32_16x16x32_bf16(af[a], bf[b], acc[a][b], 0, 0, 0);
  }
  __syncthreads();
  float* lt = (w < 2) ? ((float*)Xs + w * 1280) : ((float*)Wl + (w - 2) * 1280);
#pragma unroll
  for (int a = 0; a < 4; ++a) {
    int oTile = wm * 64 + a * 16;
    if (o0 + oTile >= O) continue;
    float scr[4], shr[4];
#pragma unroll
    for (int r = 0; r < 4; ++r) {
      scr[r] = scsh[oTile + q * 4 + r];
      shr[r] = scsh[128 + oTile + q * 4 + r];
    }
#pragma unroll
    for (int b = 0; b < 4; ++b) {
      int nl = b * 16 + l15;
      f32x4 v;
#pragma unroll
      for (int r = 0; r < 4; ++r) {
        float x = acc[a][b][r] * scr[r] + shr[r];
        if (RELU) x = fmaxf(x, 0.f);
        v[r] = x;
      }
      *(f32x4*)&lt[nl * 20 + q * 4] = v;
    }
#pragma unroll
    for (int g = 0; g < 4; ++g) {
      int nl = g * 16 + (lane >> 2);
      int ob = (lane & 3) * 4;
      f32x4 v = *(const f32x4*)&lt[nl * 20 + ob];
      ushort4 u;
      u.x = f2b(v[0]); u.y = f2b(v[1]); u.z = f2b(v[2]); u.w = f2b(v[3]);
      *(ushort4*)(Y + (size_t)(n0 + wn * 64 + nl) * ldY + o0 + oTile + ob) = u;
    }
  }
}

// ---------------- fused tail: score head (blocks 0..1023), L2-norm (1024..2047), xyz copy (2048..2095)
__global__ __launch_bounds__(256) void k_tail(const unsigned short* __restrict__ S,
                                              const unsigned short* __restrict__ FP,
                                              const float* __restrict__ wv,
                                              const float* __restrict__ bv,
                                              const float* __restrict__ pxyz,
                                              float* __restrict__ out) {
  int b = blockIdx.x;
  int t = threadIdx.x, lane = t & 63, w = t >> 6;
  if (b < 1024) {
    int row = b * 16 + w * 4 + (lane >> 4);
    int col8 = (lane & 15) * 8;
    uint4 raw = *(const uint4*)(S + (size_t)row * 128 + col8);
    float4 w0 = *(const float4*)(wv + col8);
    float4 w1 = *(const float4*)(wv + col8 + 4);
    float acc = blo(raw.x) * w0.x + bhi(raw.x) * w0.y + blo(raw.y) * w0.z + bhi(raw.y) * w0.w +
                blo(raw.z) * w1.x + bhi(raw.z) * w1.y + blo(raw.w) * w1.z + bhi(raw.w) * w1.w;
    acc += __shfl_xor(acc, 1); acc += __shfl_xor(acc, 2);
    acc += __shfl_xor(acc, 4); acc += __shfl_xor(acc, 8);
    if ((lane & 15) == 0) out[49152 + row] = 1.f / (1.f + expf(-(acc + bv[0])));
  } else if (b < 2048) {
    int row = (b - 1024) * 16 + w * 4 + (lane >> 4);
    int col8 = (lane & 15) * 8;
    uint4 raw = *(const uint4*)(FP + (size_t)row * 128 + col8);
    float v[8] = {blo(raw.x), bhi(raw.x), blo(raw.y), bhi(raw.y),
                  blo(raw.z), bhi(raw.z), blo(raw.w), bhi(raw.w)};
    float s = 0.f;
#pragma unroll
    for (int i = 0; i < 8; ++i) s = fmaf(v[i], v[i], s);
    s += __shfl_xor(s, 1); s += __shfl_xor(s, 2);
    s += __shfl_xor(s, 4); s += __shfl_xor(s, 8);
    float inv = 1.f / fmaxf(sqrtf(s), 1e-12f);
    float* op = out + 65536 + (size_t)row * 128 + col8;
    *(float4*)op = make_float4(v[0] * inv, v[1] * inv, v[2] * inv, v[3] * inv);
    *(float4*)(op + 4) = make_float4(v[4] * inv, v[5] * inv, v[6] * inv, v[7] * inv);
  } else {
    int i = (b - 2048) * 256 + t;
    ((float4*)out)[i] = ((const float4*)pxyz)[i];
  }
}

extern "C" void kernel_launch(void* const* d_in, const int* in_sizes, int n_in,
                              void* d_out, int out_size, void* d_ws, size_t ws_size,
                              hipStream_t stream) {
  const float* pcd_xyz = (const float*)d_in[0];
  const float* rgb_xyz = (const float*)d_in[1];
  const float* pcd_f   = (const float*)d_in[2];
  const float* rgb_f   = (const float*)d_in[3];
  const float* cc1_w = (const float*)d_in[4];  const float* cc1_b = (const float*)d_in[5];
  const float* cc_bn = (const float*)d_in[6];
  const float* cc2_w = (const float*)d_in[7];  const float* cc2_b = (const float*)d_in[8];
  const float* co1_w = (const float*)d_in[9];  const float* co1_b = (const float*)d_in[10];
  const float* co_bn = (const float*)d_in[11];
  const float* co2_w = (const float*)d_in[12]; const float* co2_b = (const float*)d_in[13];
  const float* dh1_w = (const float*)d_in[14]; const float* dh1_b = (const float*)d_in[15];
  const float* dh1_bn = (const float*)d_in[16];
  const float* dh2_w = (const float*)d_in[17]; const float* dh2_b = (const float*)d_in[18];
  const float* dh2_bn = (const float*)d_in[19];
  const float* dh3_w = (const float*)d_in[20]; const float* dh3_b = (const float*)d_in[21];
  const float* sh1_w = (const float*)d_in[22]; const float* sh1_b = (const float*)d_in[23];
  const float* sh_bn = (const float*)d_in[24];
  const float* sh2_w = (const float*)d_in[25]; const float* sh2_b = (const float*)d_in[26];

  char* ws = (char*)d_ws;
  float* out = (float*)d_out;

  unsigned short* wb    = (unsigned short*)(ws);              // 766 KB
  unsigned short* rgbTb = (unsigned short*)(ws + 0x100000);   // 2.1 MB
  float4* rxyz4         = (float4*)(ws + 0x320000);           // 128 KB
  int*   nb  = (int*)(ws + 0x340000);                         // 192 KB
  float* pd  = (float*)(ws + 0x400000);                       // 1.5 MB
  int*   pi  = (int*)(ws + 0x700000);                         // 1.5 MB
  unsigned short* xcat = (unsigned short*)(ws + 0xA00000);    // (NP,384)
  unsigned short* h1   = (unsigned short*)(ws + 0x1700000);   // (NP,384)
  unsigned short* x2   = (unsigned short*)(ws + 0x2300000);   // (NP,256)
  unsigned short* h2   = (unsigned short*)(ws + 0x2B00000);   // (NP,256)
  unsigned short* full = (unsigned short*)(ws + 0x3300000);   // (NP,160)
  unsigned short* h3   = (unsigned short*)(ws + 0x3900000);   // (NP,160)
  unsigned short* h4   = (unsigned short*)(ws + 0x3F00000);   // (NP,160)
  unsigned short* fp   = (unsigned short*)(ws + 0x4500000);   // (NP,128)
  unsigned short* sB   = (unsigned short*)(ws + 0x4A00000);   // (NP,128)

  unsigned short* wb_cc1 = wb;
  unsigned short* wb_cc2 = wb + 147456;
  unsigned short* wb_co1 = wb + 196608;
  unsigned short* wb_co2 = wb + 262144;
  unsigned short* wb_dh1 = wb + 294912;
  unsigned short* wb_dh2 = wb + 320512;
  unsigned short* wb_dh3 = wb + 346112;
  unsigned short* wb_sh1 = wb + 366592;

  k_wconv<<<dim3(72, 8), 256, 0, stream>>>(cc1_w, cc2_w, co1_w, co2_w, dh1_w, dh2_w, dh3_w, sh1_w, wb);
  k_transpose_rgb<<<128, 256, 0, stream>>>(rgb_f, rgb_xyz, rgbTb, rxyz4);
  k_nn_part<<<dim3(256, 8), 256, 0, stream>>>(pcd_xyz, rxyz4, pd, pi);
  k_nn_merge<<<64, 256, 0, stream>>>(pd, pi, nb);
  k_gather_max<<<4096, 256, 0, stream>>>(rgbTb, nb, xcat, x2);
  k_transpose_pcd<<<256, 256, 0, stream>>>(pcd_f, full);

  k_bgemm<true, true><<<dim3(128, 3), 256, 0, stream>>>(wb_cc1, cc1_b, cc_bn, xcat, h1, 384, 384, 384);
  k_bgemm<false, false><<<dim3(128, 1), 256, 0, stream>>>(wb_cc2, cc2_b, nullptr, h1, x2, 128, 384, 256);
  k_bgemm<true, true><<<dim3(128, 2), 256, 0, stream>>>(wb_co1, co1_b, co_bn, x2, h2, 256, 256, 256);
  k_bgemm<false, false><<<dim3(128, 1), 256, 0, stream>>>(wb_co2, co2_b, nullptr, h2, full + 32, 128, 256, 160);
  k_bgemm<true, true><<<dim3(128, 2), 256, 0, stream>>>(wb_dh1, dh1_b, dh1_bn, full, h3, 160, 160, 160);
  k_bgemm<true, true><<<dim3(128, 2), 256, 0, stream>>>(wb_dh2, dh2_b, dh2_bn, h3, h4, 160, 160, 160);
  k_bgemm<false, false><<<dim3(128, 1), 256, 0, stream>>>(wb_dh3, dh3_b, nullptr, h4, fp, 128, 160, 128);
  k_bgemm<true, true><<<dim3(128, 1), 256, 0, stream>>>(wb_sh1, sh1_b, sh_bn, fp, sB, 128, 128, 128);

  k_tail<<<2096, 256, 0, stream>>>(sB, fp, sh2_w, sh2_b, pcd_xyz, out);
}

// Round 7
// 234.382 us; speedup vs baseline: 1.2782x; 1.0830x over previous
//
#include <hip/hip_runtime.h>
#include <math.h>

#define NP 16384
#define NR 8192

typedef __attribute__((ext_vector_type(8))) short short8;
typedef __attribute__((ext_vector_type(4))) float f32x4;

__device__ inline unsigned short f2b(float f) {
  unsigned int x = __float_as_uint(f);
  return (unsigned short)((x + 0x7FFFu + ((x >> 16) & 1u)) >> 16);  // RNE
}
__device__ inline float blo(unsigned int u) { return __uint_as_float(u << 16); }
__device__ inline float bhi(unsigned int u) { return __uint_as_float(u & 0xffff0000u); }

// ---------------- fused preprocessing: blocks 0..127 rgb transpose (+rxyz4 pack),
// 128..383 pcd transpose, 384..959 weight f32->bf16 conversion
__global__ __launch_bounds__(256) void k_pre(const float* __restrict__ rf,
                                             const float* __restrict__ rxyz,
                                             const float* __restrict__ pf,
                                             const float* __restrict__ s0, const float* __restrict__ s1,
                                             const float* __restrict__ s2, const float* __restrict__ s3,
                                             const float* __restrict__ s4, const float* __restrict__ s5,
                                             const float* __restrict__ s6, const float* __restrict__ s7,
                                             unsigned short* __restrict__ rgbTb,
                                             float4* __restrict__ rxyz4,
                                             unsigned short* __restrict__ full,
                                             unsigned short* __restrict__ dst) {
  __shared__ float tile[128][65];
  int b = blockIdx.x, t = threadIdx.x;
  if (b < 128) {
    int r0 = b * 64;
    for (int e = 0; e < 32; ++e) {
      int idx = t + e * 256;
      int c = idx >> 6, rl = idx & 63;
      tile[c][rl] = rf[c * NR + r0 + rl];
    }
    __syncthreads();
    for (int e = 0; e < 32; ++e) {
      int idx = t + e * 256;
      int rl = idx >> 7, c = idx & 127;
      rgbTb[(size_t)(r0 + rl) * 128 + c] = f2b(tile[c][rl]);
    }
    if (b == 0 && t < 128) rgbTb[(size_t)NR * 128 + t] = 0;
    if ((t >> 6) == 0) {
      int i = r0 + (t & 63);
      float x = rxyz[i * 3], y = rxyz[i * 3 + 1], z = rxyz[i * 3 + 2];
      rxyz4[i] = make_float4(x, y, z, fmaf(x, x, fmaf(y, y, z * z)));
    }
  } else if (b < 384) {
    int n0 = (b - 128) * 64;
    for (int e = 0; e < 8; ++e) {
      int idx = t + e * 256;
      int c = idx >> 6, nl = idx & 63;
      tile[c][nl] = pf[c * NP + n0 + nl];
    }
    __syncthreads();
    for (int e = 0; e < 8; ++e) {
      int idx = t + e * 256;
      int nl = idx >> 5, c = idx & 31;
      full[(size_t)(n0 + nl) * 160 + c] = f2b(tile[c][nl]);
    }
  } else {
    const int sizes[8] = {147456, 49152, 65536, 32768, 25600, 25600, 20480, 16384};
    const int offs[8]  = {0, 147456, 196608, 262144, 294912, 320512, 346112, 366592};
    const float* srcs[8] = {s0, s1, s2, s3, s4, s5, s6, s7};
    int j = b - 384;
    int m = j / 72, bx = j % 72;
    int i = (bx * 256 + t) * 8;
    if (i >= sizes[m]) return;
    const float4* sp = (const float4*)(srcs[m] + i);
    float4 a = sp[0], c = sp[1];
    uint4 o;
    o.x = f2b(a.x) | ((unsigned int)f2b(a.y) << 16);
    o.y = f2b(a.z) | ((unsigned int)f2b(a.w) << 16);
    o.z = f2b(c.x) | ((unsigned int)f2b(c.y) << 16);
    o.w = f2b(c.z) | ((unsigned int)f2b(c.w) << 16);
    *(uint4*)(dst + offs[m] + i) = o;
  }
}

// ---------------- three_nn partials (unchanged from R6-passing version)
__global__ __launch_bounds__(256) void k_nn_part(const float* __restrict__ pxyz,
                                                 const float4* __restrict__ rxyz4,
                                                 float* __restrict__ pd,
                                                 int* __restrict__ pi) {
  __shared__ float4 pts[1024];
  __shared__ float msd[4][3][64];
  __shared__ int   mid[4][3][64];
  int t = threadIdx.x;
  int g = blockIdx.x, s = blockIdx.y;
  int lane = t & 63, w = t >> 6;
  int rbase = s * 1024;
#pragma unroll
  for (int e = 0; e < 4; ++e) {
    int q = t + e * 256;
    pts[q] = rxyz4[rbase + q];
  }
  int n = g * 64 + lane;
  float px = pxyz[n * 3], py = pxyz[n * 3 + 1], pz = pxyz[n * 3 + 2];
  float pp = fmaf(px, px, fmaf(py, py, pz * pz));
  float nx2 = -2.f * px, ny2 = -2.f * py, nz2 = -2.f * pz;
  __syncthreads();
  const float R2L = 0.005626125f;          // 0.075^2 * 1.0002 sentinel (> R2 -> masks to NR)
  const float MARGIN = 4e-6f;              // covers fp32 error of expanded form
  float s0 = R2L, s1 = R2L, s2 = R2L;
  int i0 = 0, i1 = 0, i2 = 0;
  float thr = R2L + MARGIN - pp;
  int base = w * 256;
#pragma unroll 8
  for (int loc = 0; loc < 256; ++loc) {
    float4 r = pts[base + loc];            // wave-uniform address -> LDS broadcast
    float e3 = fmaf(nz2, r.z, fmaf(ny2, r.y, fmaf(nx2, r.x, r.w)));
    if (__ballot(e3 < thr)) {              // wave-uniform branch
      float dx = px - r.x, dy = py - r.y, dz = pz - r.z;
      float d2 = fmaf(dx, dx, fmaf(dy, dy, dz * dz));
      if (d2 < s2) {                       // exact strict <: reference tie-break
        int i = rbase + base + loc;
        if (d2 < s1) {
          s2 = s1; i2 = i1;
          if (d2 < s0) { s1 = s0; i1 = i0; s0 = d2; i0 = i; }
          else         { s1 = d2; i1 = i; }
        } else { s2 = d2; i2 = i; }
      }
      thr = s2 + MARGIN - pp;
    }
  }
  msd[w][0][lane] = s0; msd[w][1][lane] = s1; msd[w][2][lane] = s2;
  mid[w][0][lane] = i0; mid[w][1][lane] = i1; mid[w][2][lane] = i2;
  __syncthreads();
  if (t < 64) {
    s0 = msd[0][0][t]; s1 = msd[0][1][t]; s2 = msd[0][2][t];
    i0 = mid[0][0][t]; i1 = mid[0][1][t]; i2 = mid[0][2][t];
    for (int ww = 1; ww < 4; ++ww) {       // ascending candidate order
      for (int q = 0; q < 3; ++q) {
        float d2 = msd[ww][q][t]; int i = mid[ww][q][t];
        if (d2 < s2) {
          if (d2 < s1) {
            s2 = s1; i2 = i1;
            if (d2 < s0) { s1 = s0; i1 = i0; s0 = d2; i0 = i; }
            else         { s1 = d2; i1 = i; }
          } else { s2 = d2; i2 = i; }
        }
      }
    }
    int off = ((g * 8 + s) * 64 + t) * 3;
    pd[off + 0] = s0; pd[off + 1] = s1; pd[off + 2] = s2;
    pi[off + 0] = i0; pi[off + 1] = i1; pi[off + 2] = i2;
  }
}

// ---------------- fused merge + gather + max: one wave per point.
// Merge = 3x lexicographic (d2,idx) wave-min over 24 partial candidates; equal-d2 ties
// resolve to smaller idx = reference top_k semantics. Sentinel entries (d2=R2L) sort
// after all real candidates (d2 < R2L strictly) and mask to NR, so duplicate-sentinel
// clearing is harmless.
__global__ __launch_bounds__(256) void k_gather_max(const unsigned short* __restrict__ rgbTb,
                                                    const float* __restrict__ pd,
                                                    const int* __restrict__ pi,
                                                    unsigned short* __restrict__ xcat,
                                                    unsigned short* __restrict__ x2) {
  int t = threadIdx.x, lane = t & 63, w = t >> 6;
  int n = blockIdx.x * 4 + w;
  int g = n >> 6, l = n & 63;
  unsigned long long key = ~0ull;
  if (lane < 24) {
    int s = lane / 3, qq = lane % 3;
    int off = ((g * 8 + s) * 64 + l) * 3 + qq;
    key = ((unsigned long long)__float_as_uint(pd[off]) << 32) | (unsigned int)pi[off];
  }
  unsigned long long mk[3];
#pragma unroll
  for (int r = 0; r < 3; ++r) {
    unsigned long long m = key;
#pragma unroll
    for (int o = 1; o < 64; o <<= 1) {
      unsigned long long other = __shfl_xor(m, o);
      m = other < m ? other : m;
    }
    mk[r] = m;
    if (key == m) key = ~0ull;
  }
  const float R2 = 0.075f * 0.075f;
  float d0 = __uint_as_float((unsigned int)(mk[0] >> 32));
  float d1 = __uint_as_float((unsigned int)(mk[1] >> 32));
  float d2 = __uint_as_float((unsigned int)(mk[2] >> 32));
  int j0 = (d0 > R2) ? NR : (int)(mk[0] & 0xffffffffu);
  int j1 = (d1 > R2) ? NR : (int)(mk[1] & 0xffffffffu);
  int j2 = (d2 > R2) ? NR : (int)(mk[2] & 0xffffffffu);
  unsigned int a = ((const unsigned int*)(rgbTb + (size_t)j0 * 128))[lane];
  unsigned int b = ((const unsigned int*)(rgbTb + (size_t)j1 * 128))[lane];
  unsigned int c = ((const unsigned int*)(rgbTb + (size_t)j2 * 128))[lane];
  unsigned int* xr = (unsigned int*)(xcat + (size_t)n * 384);
  xr[lane] = a; xr[64 + lane] = b; xr[128 + lane] = c;
  float ml = fmaxf(blo(a), fmaxf(blo(b), blo(c)));
  float mh = fmaxf(bhi(a), fmaxf(bhi(b), bhi(c)));
  unsigned int m = (__float_as_uint(mh) & 0xffff0000u) | (__float_as_uint(ml) >> 16);
  ((unsigned int*)(x2 + (size_t)n * 256 + 128))[lane] = m;
}

// ---------------- bf16 MFMA GEMM (unchanged, front chain only)
template <bool BN, bool RELU>
__global__ __launch_bounds__(256) void k_bgemm(const unsigned short* __restrict__ Wb,
                                               const float* __restrict__ bias,
                                               const float* __restrict__ bnp,
                                               const unsigned short* __restrict__ X,
                                               unsigned short* __restrict__ Y,
                                               int O, int C, int ldY) {
  __shared__ unsigned short Xs[128 * 40];
  __shared__ unsigned short Wl[128 * 40];
  __shared__ float scsh[256];
  int t = threadIdx.x;
  int lane = t & 63, w = t >> 6;
  int wn = w & 1, wm = w >> 1;
  int q = lane >> 4, l15 = lane & 15;
  int n0 = blockIdx.x * 128, o0 = blockIdx.y * 128;
  if (t < 128) {
    int o = o0 + t;
    float sc = 0.f, sh = 0.f;
    if (o < O) {
      float b = bias[o];
      if (BN) {
        float g = bnp[o], be = bnp[O + o], m = bnp[2 * O + o], v = bnp[3 * O + o];
        float inv = g * rsqrtf(v + 1e-5f);
        sc = inv; sh = (b - m) * inv + be;
      } else { sc = 1.f; sh = b; }
    }
    scsh[t] = sc; scsh[128 + t] = sh;
  }
  f32x4 acc[4][4] = {};
  for (int c0 = 0; c0 < C; c0 += 32) {
    __syncthreads();
#pragma unroll
    for (int e = 0; e < 2; ++e) {
      int idx = e * 256 + t;
      int row = idx >> 2, kb = idx & 3;
      uint4 xv = *(const uint4*)(X + (size_t)(n0 + row) * C + c0 + kb * 8);
      *(uint4*)&Xs[row * 40 + kb * 8] = xv;
      int go = o0 + row; if (go >= O) go = O - 1;
      uint4 wv = *(const uint4*)(Wb + (size_t)go * C + c0 + kb * 8);
      *(uint4*)&Wl[row * 40 + kb * 8] = wv;
    }
    __syncthreads();
    short8 af[4], bf[4];
#pragma unroll
    for (int a = 0; a < 4; ++a)
      af[a] = *(const short8*)&Wl[(wm * 64 + a * 16 + l15) * 40 + q * 8];
#pragma unroll
    for (int b = 0; b < 4; ++b)
      bf[b] = *(const short8*)&Xs[(wn * 64 + b * 16 + l15) * 40 + q * 8];
#pragma unroll
    for (int a = 0; a < 4; ++a)
#pragma unroll
      for (int b = 0; b < 4; ++b)
        acc[a][b] = __builtin_amdgcn_mfma_f32_16x16x32_bf16(af[a], bf[b], acc[a][b], 0, 0, 0);
  }
  __syncthreads();
  float* lt = (w < 2) ? ((float*)Xs + w * 1280) : ((float*)Wl + (w - 2) * 1280);
#pragma unroll
  for (int a = 0; a < 4; ++a) {
    int oTile = wm * 64 + a * 16;
    if (o0 + oTile >= O) continue;
    float scr[4], shr[4];
#pragma unroll
    for (int r = 0; r < 4; ++r) {
      scr[r] = scsh[oTile + q * 4 + r];
      shr[r] = scsh[128 + oTile + q * 4 + r];
    }
#pragma unroll
    for (int b = 0; b < 4; ++b) {
      int nl = b * 16 + l15;
      f32x4 v;
#pragma unroll
      for (int r = 0; r < 4; ++r) {
        float x = acc[a][b][r] * scr[r] + shr[r];
        if (RELU) x = fmaxf(x, 0.f);
        v[r] = x;
      }
      *(f32x4*)&lt[nl * 20 + q * 4] = v;
    }
#pragma unroll
    for (int g = 0; g < 4; ++g) {
      int nl = g * 16 + (lane >> 2);
      int ob = (lane & 3) * 4;
      f32x4 v = *(const f32x4*)&lt[nl * 20 + ob];
      ushort4 u;
      u.x = f2b(v[0]); u.y = f2b(v[1]); u.z = f2b(v[2]); u.w = f2b(v[3]);
      *(ushort4*)(Y + (size_t)(n0 + wn * 64 + nl) * ldY + o0 + oTile + ob) = u;
    }
  }
}

// ---------------- fused back chain layer: Y[n][o] = act(sc*(W.X)+sh), wave-local rows
template <int C, int O, bool BN, bool RELU>
__device__ __forceinline__ void back_layer(const unsigned short* __restrict__ W,
                                           const float* __restrict__ bias,
                                           const float* __restrict__ bnp,
                                           const unsigned short* Xs,
                                           unsigned short* Ys,
                                           unsigned short* Wl, float* scsh, float* lt,
                                           int t, int w, int q, int l15, int lane) {
  f32x4 acc[O / 16];
#pragma unroll
  for (int i = 0; i < O / 16; ++i) acc[i] = (f32x4){0.f, 0.f, 0.f, 0.f};
#pragma unroll
  for (int k0 = 0; k0 < C; k0 += 32) {
    __syncthreads();                       // prev layer epilogue / prev chunk reads done
    if (k0 == 0 && t < O) {
      float b = bias[t], sc, sh;
      if (BN) {
        float g = bnp[t], be = bnp[O + t], m = bnp[2 * O + t], v = bnp[3 * O + t];
        float inv = g * rsqrtf(v + 1e-5f);
        sc = inv; sh = (b - m) * inv + be;
      } else { sc = 1.f; sh = b; }
      scsh[t] = sc; scsh[160 + t] = sh;
    }
    for (int idx = t; idx < O * 4; idx += 256) {
      int row = idx >> 2, kb = idx & 3;
      *(uint4*)&Wl[row * 40 + kb * 8] = *(const uint4*)(W + (size_t)row * C + k0 + kb * 8);
    }
    __syncthreads();
    short8 bf = *(const short8*)&Xs[(w * 16 + l15) * 168 + k0 + q * 8];
#pragma unroll
    for (int ot = 0; ot < O / 16; ++ot) {
      short8 af = *(const short8*)&Wl[(ot * 16 + l15) * 40 + q * 8];
      acc[ot] = __builtin_amdgcn_mfma_f32_16x16x32_bf16(af, bf, acc[ot], 0, 0, 0);
    }
  }
  // epilogue: wave-local transpose to bf16 rows (same-wave DS ordering)
#pragma unroll
  for (int ot = 0; ot < O / 16; ++ot) {
    f32x4 v;
#pragma unroll
    for (int r = 0; r < 4; ++r) {
      float x = acc[ot][r] * scsh[ot * 16 + q * 4 + r] + scsh[160 + ot * 16 + q * 4 + r];
      if (RELU) x = fmaxf(x, 0.f);
      v[r] = x;
    }
    *(f32x4*)&lt[l15 * 20 + q * 4] = v;
    f32x4 tv = *(const f32x4*)&lt[(lane >> 2) * 20 + (lane & 3) * 4];
    ushort4 u;
    u.x = f2b(tv[0]); u.y = f2b(tv[1]); u.z = f2b(tv[2]); u.w = f2b(tv[3]);
    *(ushort4*)&Ys[(w * 16 + (lane >> 2)) * 168 + ot * 16 + (lane & 3) * 4] = u;
  }
}

// ---------------- fused back chain: dh1->dh2->dh3->sh1->score/norm/xyz, 64 rows/block
__global__ __launch_bounds__(256) void k_back(const unsigned short* __restrict__ w1,
                                              const unsigned short* __restrict__ w2,
                                              const unsigned short* __restrict__ w3,
                                              const unsigned short* __restrict__ w4,
                                              const float* __restrict__ b1, const float* __restrict__ bn1,
                                              const float* __restrict__ b2, const float* __restrict__ bn2,
                                              const float* __restrict__ b3,
                                              const float* __restrict__ b4, const float* __restrict__ bn4,
                                              const float* __restrict__ wv, const float* __restrict__ bv,
                                              const unsigned short* __restrict__ full,
                                              const float* __restrict__ pxyz,
                                              float* __restrict__ out) {
  __shared__ unsigned short Xb[64 * 168];
  __shared__ unsigned short Yb[64 * 168];
  __shared__ unsigned short Wl[160 * 40];
  __shared__ float scsh[320];
  __shared__ float tscr[4][320];
  int t = threadIdx.x, lane = t & 63, w = t >> 6;
  int q = lane >> 4, l15 = lane & 15;
  int n0 = blockIdx.x * 64;
  for (int idx = t; idx < 1280; idx += 256) {     // load X: 64 rows x 160 (20 uint4/row)
    int row = idx / 20, c8 = idx % 20;
    *(uint4*)&Xb[row * 168 + c8 * 8] = *(const uint4*)(full + (size_t)(n0 + row) * 160 + c8 * 8);
  }
  float* lt = tscr[w];
  back_layer<160, 160, true,  true >(w1, b1, bn1, Xb, Yb, Wl, scsh, lt, t, w, q, l15, lane);
  back_layer<160, 160, true,  true >(w2, b2, bn2, Yb, Xb, Wl, scsh, lt, t, w, q, l15, lane);
  back_layer<160, 128, false, false>(w3, b3, nullptr, Xb, Yb, Wl, scsh, lt, t, w, q, l15, lane); // fp -> Yb
  back_layer<128, 128, true,  true >(w4, b4, bn4, Yb, Xb, Wl, scsh, lt, t, w, q, l15, lane);     // s  -> Xb
  // tail (wave-local rows): score from Xb, norm from Yb
  int col8 = (lane & 15) * 8;
  float4 w0 = *(const float4*)(wv + col8);
  float4 wA = *(const float4*)(wv + col8 + 4);
  float bvv = bv[0];
#pragma unroll
  for (int gi = 0; gi < 4; ++gi) {
    int row = w * 16 + gi * 4 + (lane >> 4);
    uint4 raw = *(const uint4*)&Xb[row * 168 + col8];
    float acc = blo(raw.x) * w0.x + bhi(raw.x) * w0.y + blo(raw.y) * w0.z + bhi(raw.y) * w0.w +
                blo(raw.z) * wA.x + bhi(raw.z) * wA.y + blo(raw.w) * wA.z + bhi(raw.w) * wA.w;
    acc += __shfl_xor(acc, 1); acc += __shfl_xor(acc, 2);
    acc += __shfl_xor(acc, 4); acc += __shfl_xor(acc, 8);
    if ((lane & 15) == 0) out[49152 + n0 + row] = 1.f / (1.f + expf(-(acc + bvv)));
    uint4 rf = *(const uint4*)&Yb[row * 168 + col8];
    float v[8] = {blo(rf.x), bhi(rf.x), blo(rf.y), bhi(rf.y),
                  blo(rf.z), bhi(rf.z), blo(rf.w), bhi(rf.w)};
    float s = 0.f;
#pragma unroll
    for (int i = 0; i < 8; ++i) s = fmaf(v[i], v[i], s);
    s += __shfl_xor(s, 1); s += __shfl_xor(s, 2);
    s += __shfl_xor(s, 4); s += __shfl_xor(s, 8);
    float inv = 1.f / fmaxf(sqrtf(s), 1e-12f);
    float* op = out + 65536 + (size_t)(n0 + row) * 128 + col8;
    *(float4*)op = make_float4(v[0] * inv, v[1] * inv, v[2] * inv, v[3] * inv);
    *(float4*)(op + 4) = make_float4(v[4] * inv, v[5] * inv, v[6] * inv, v[7] * inv);
  }
  for (int i = t; i < 192; i += 256) out[n0 * 3 + i] = pxyz[n0 * 3 + i];
}

extern "C" void kernel_launch(void* const* d_in, const int* in_sizes, int n_in,
                              void* d_out, int out_size, void* d_ws, size_t ws_size,
                              hipStream_t stream) {
  const float* pcd_xyz = (const float*)d_in[0];
  const float* rgb_xyz = (const float*)d_in[1];
  const float* pcd_f   = (const float*)d_in[2];
  const float* rgb_f   = (const float*)d_in[3];
  const float* cc1_w = (const float*)d_in[4];  const float* cc1_b = (const float*)d_in[5];
  const float* cc_bn = (const float*)d_in[6];
  const float* cc2_w = (const float*)d_in[7];  const float* cc2_b = (const float*)d_in[8];
  const float* co1_w = (const float*)d_in[9];  const float* co1_b = (const float*)d_in[10];
  const float* co_bn = (const float*)d_in[11];
  const float* co2_w = (const float*)d_in[12]; const float* co2_b = (const float*)d_in[13];
  const float* dh1_w = (const float*)d_in[14]; const float* dh1_b = (const float*)d_in[15];
  const float* dh1_bn = (const float*)d_in[16];
  const float* dh2_w = (const float*)d_in[17]; const float* dh2_b = (const float*)d_in[18];
  const float* dh2_bn = (const float*)d_in[19];
  const float* dh3_w = (const float*)d_in[20]; const float* dh3_b = (const float*)d_in[21];
  const float* sh1_w = (const float*)d_in[22]; const float* sh1_b = (const float*)d_in[23];
  const float* sh_bn = (const float*)d_in[24];
  const float* sh2_w = (const float*)d_in[25]; const float* sh2_b = (const float*)d_in[26];

  char* ws = (char*)d_ws;
  float* out = (float*)d_out;

  unsigned short* wb    = (unsigned short*)(ws);              // 766 KB
  unsigned short* rgbTb = (unsigned short*)(ws + 0x100000);   // 2.1 MB
  float4* rxyz4         = (float4*)(ws + 0x320000);           // 128 KB
  float* pd  = (float*)(ws + 0x400000);                       // 1.5 MB
  int*   pi  = (int*)(ws + 0x700000);                         // 1.5 MB
  unsigned short* xcat = (unsigned short*)(ws + 0xA00000);    // (NP,384)
  unsigned short* h1   = (unsigned short*)(ws + 0x1700000);   // (NP,384)
  unsigned short* x2   = (unsigned short*)(ws + 0x2300000);   // (NP,256)
  unsigned short* h2   = (unsigned short*)(ws + 0x2B00000);   // (NP,256)
  unsigned short* full = (unsigned short*)(ws + 0x3300000);   // (NP,160)

  unsigned short* wb_cc1 = wb;
  unsigned short* wb_cc2 = wb + 147456;
  unsigned short* wb_co1 = wb + 196608;
  unsigned short* wb_co2 = wb + 262144;
  unsigned short* wb_dh1 = wb + 294912;
  unsigned short* wb_dh2 = wb + 320512;
  unsigned short* wb_dh3 = wb + 346112;
  unsigned short* wb_sh1 = wb + 366592;

  k_pre<<<960, 256, 0, stream>>>(rgb_f, rgb_xyz, pcd_f,
                                 cc1_w, cc2_w, co1_w, co2_w, dh1_w, dh2_w, dh3_w, sh1_w,
                                 rgbTb, rxyz4, full, wb);
  k_nn_part<<<dim3(256, 8), 256, 0, stream>>>(pcd_xyz, rxyz4, pd, pi);
  k_gather_max<<<4096, 256, 0, stream>>>(rgbTb, pd, pi, xcat, x2);

  k_bgemm<true, true><<<dim3(128, 3), 256, 0, stream>>>(wb_cc1, cc1_b, cc_bn, xcat, h1, 384, 384, 384);
  k_bgemm<false, false><<<dim3(128, 1), 256, 0, stream>>>(wb_cc2, cc2_b, nullptr, h1, x2, 128, 384, 256);
  k_bgemm<true, true><<<dim3(128, 2), 256, 0, stream>>>(wb_co1, co1_b, co_bn, x2, h2, 256, 256, 256);
  k_bgemm<false, false><<<dim3(128, 1), 256, 0, stream>>>(wb_co2, co2_b, nullptr, h2, full + 32, 128, 256, 160);

  k_back<<<256, 256, 0, stream>>>(wb_dh1, wb_dh2, wb_dh3, wb_sh1,
                                  dh1_b, dh1_bn, dh2_b, dh2_bn, dh3_b, sh1_b, sh_bn,
                                  sh2_w, sh2_b, full, pcd_xyz, out);
}